// Round 1
// 119.960 us; speedup vs baseline: 1.0233x; 1.0233x over previous
//
#include <hip/hip_runtime.h>

// Problem constants (fixed by reference setup_inputs)
#define N_TOTAL 8388608
#define SEG 64
#define NSEG (N_TOTAL / SEG)            // 131072 segments
#define TPB 256
#define BLOCKS 2048                     // 8 blocks/CU = 32 waves/CU: ONE resident generation
#define WAVES (BLOCKS * TPB / 64)       // 8192 waves
#define SPW 4                           // segments per wave-iteration (4 x 16-lane groups)
#define ITERS (NSEG / (WAVES * SPW))    // 4 iterations per wave (exact)

// DPP ctrl encodings (gfx9/CDNA):
//   quad_perm [1,0,3,2] = 0xB1 (lane^1), [2,3,0,1] = 0x4E (lane^2),
//   [3,2,1,0] = 0x1B (mirror-in-quad), ROW_MIRROR = 0x140 (lane -> 15-lane in row),
//   ROW_HALF_MIRROR = 0x141 (mirror within 8), row_shr:N = 0x110|N
template <int CTRL>
__device__ __forceinline__ unsigned dppmov(unsigned v) {
    return (unsigned)__builtin_amdgcn_update_dpp(0, (int)v, CTRL, 0xf, 0xf, true);
}
template <int CTRL>
__device__ __forceinline__ float dpp_addf(float x) {
    int mv = __builtin_amdgcn_update_dpp(0, __float_as_int(x), CTRL, 0xf, 0xf, true);
    return x + __int_as_float(mv);
}
__device__ __forceinline__ unsigned umn(unsigned a, unsigned b) { return a < b ? a : b; }
__device__ __forceinline__ unsigned umx(unsigned a, unsigned b) { return a > b ? a : b; }

// One wave processes FOUR 64-element segments per iteration:
//   16-lane group g = lane>>4 owns one segment; lane q = lane&15 holds
//   elements e = 4q..4q+3 (registers k0..k3).
// ASCENDING mirror-form bitonic sort of keys (t<<6)|(63-e) == exact reverse
// of the reference's stable descending argsort(-t) (keys distinct).
// Mirror-form => every comparator is ascending (min to lower index): no
// direction masks; mirrors map to DPP quad_perm/ROW_MIRROR/ROW_HALF_MIRROR.
// Only ONE ds_swizzle stage (lane^4) per sort. z gathered via a same-wave
// LDS round-trip; prefix scan is pure row_shr DPP within 16-lane rows.
__global__ __launch_bounds__(TPB, 8) void mledis_seg4(
    const float4* __restrict__ mean4,
    const float4* __restrict__ var4,
    const int4*   __restrict__ tgt4,
    float* __restrict__ partial)
{
    const int lane = threadIdx.x & 63;
    const int q    = lane & 15;          // lane within 16-lane segment group
    const int wIB  = threadIdx.x >> 6;
    const int waveId = blockIdx.x * (TPB / 64) + wIB;

    __shared__ __align__(16) float zbuf[TPB / 64][64 * SPW];   // 4 KB/block
    float* const zbase = &zbuf[wIB][(lane >> 4) * 64];

    // hoisted role masks (loop-invariant; compiler keeps them in SGPR pairs)
    const bool lo1 = (q & 1) == 0;
    const bool lo2 = (q & 2) == 0;
    const bool lo4 = (q & 4) == 0;
    const bool lo8 = (q & 8) == 0;

    float4 mc = mean4[waveId * 64 + lane];
    float4 vc = var4 [waveId * 64 + lane];
    int4   tc = tgt4 [waveId * 64 + lane];

    float acc = 0.0f;

    // ascending compare-exchange between two registers (min to first)
    #define CE(a, b) { const unsigned _mn = umn(a, b); const unsigned _mx = umx(a, b); \
                       a = _mn; b = _mx; }
    // mirror merge stage: partner lane via DPP ctrl, partner holds reg 3-r
    #define MIR(CTRL, LO) { \
        const unsigned o0 = dppmov<CTRL>(k3); \
        const unsigned o1 = dppmov<CTRL>(k2); \
        const unsigned o2 = dppmov<CTRL>(k1); \
        const unsigned o3 = dppmov<CTRL>(k0); \
        k0 = (LO) ? umn(k0, o0) : umx(k0, o0); \
        k1 = (LO) ? umn(k1, o1) : umx(k1, o1); \
        k2 = (LO) ? umn(k2, o2) : umx(k2, o2); \
        k3 = (LO) ? umn(k3, o3) : umx(k3, o3); \
    }
    // xor cleanup stage via DPP (same reg from partner lane)
    #define XD(CTRL, LO) { \
        const unsigned o0 = dppmov<CTRL>(k0); \
        const unsigned o1 = dppmov<CTRL>(k1); \
        const unsigned o2 = dppmov<CTRL>(k2); \
        const unsigned o3 = dppmov<CTRL>(k3); \
        k0 = (LO) ? umn(k0, o0) : umx(k0, o0); \
        k1 = (LO) ? umn(k1, o1) : umx(k1, o1); \
        k2 = (LO) ? umn(k2, o2) : umx(k2, o2); \
        k3 = (LO) ? umn(k3, o3) : umx(k3, o3); \
    }
    // xor cleanup stage lane^4 via ds_swizzle (BitMode: (4<<10)|0x1F)
    #define XS4(LO) { \
        const unsigned o0 = (unsigned)__builtin_amdgcn_ds_swizzle((int)k0, 0x101F); \
        const unsigned o1 = (unsigned)__builtin_amdgcn_ds_swizzle((int)k1, 0x101F); \
        const unsigned o2 = (unsigned)__builtin_amdgcn_ds_swizzle((int)k2, 0x101F); \
        const unsigned o3 = (unsigned)__builtin_amdgcn_ds_swizzle((int)k3, 0x101F); \
        k0 = (LO) ? umn(k0, o0) : umx(k0, o0); \
        k1 = (LO) ? umn(k1, o1) : umx(k1, o1); \
        k2 = (LO) ? umn(k2, o2) : umx(k2, o2); \
        k3 = (LO) ? umn(k3, o3) : umx(k3, o3); \
    }

    #pragma unroll
    for (int it = 0; it < ITERS; ++it) {
        // ---- prefetch next iteration while computing this one ----
        float4 mn_, vn_; int4 tn_;
        if (it + 1 < ITERS) {
            const int b = (waveId + (it + 1) * WAVES) * 64 + lane;
            mn_ = mean4[b]; vn_ = var4[b]; tn_ = tgt4[b];
        }

        // z = exp(m + v/2); stash this lane's 4 elements in LDS (read post-sort;
        // LDS latency hides under the sort; same-wave => no barrier needed)
        const float z0 = __expf(fmaf(0.5f, vc.x, mc.x));
        const float z1 = __expf(fmaf(0.5f, vc.y, mc.y));
        const float z2 = __expf(fmaf(0.5f, vc.z, mc.z));
        const float z3 = __expf(fmaf(0.5f, vc.w, mc.w));
        *(float4*)(zbase + 4 * q) = make_float4(z0, z1, z2, z3);

        // order-invariant part: sum(v/2 - m)
        acc += fmaf(0.5f, (vc.x + vc.y) + (vc.z + vc.w),
                    -((mc.x + mc.y) + (mc.z + mc.w)));

        // distinct keys; ascending sort == reverse of stable descending argsort(-t)
        const unsigned eb = 63u - 4u * (unsigned)q;
        unsigned k0 = (((unsigned)tc.x) << 6) | eb;
        unsigned k1 = (((unsigned)tc.y) << 6) | (eb - 1u);
        unsigned k2 = (((unsigned)tc.z) << 6) | (eb - 2u);
        unsigned k3 = (((unsigned)tc.w) << 6) | (eb - 3u);

        // ---- all-ascending mirror-form bitonic sort over 64 elements ----
        // merge K=2
        CE(k0, k1); CE(k2, k3);
        // merge K=4: mirror (0<->3, 1<->2) then xor1 — all in-register, compile-time
        CE(k0, k3); CE(k1, k2);
        CE(k0, k1); CE(k2, k3);
        // merge K=8: mirror lane^1 (reg-swapped), then local xor2/xor1
        MIR(0xB1, lo1);
        CE(k0, k2); CE(k1, k3);
        CE(k0, k1); CE(k2, k3);
        // merge K=16: mirror-in-quad, xor4 = lane^1, local xor2/xor1
        MIR(0x1B, lo2);
        XD(0xB1, lo1);
        CE(k0, k2); CE(k1, k3);
        CE(k0, k1); CE(k2, k3);
        // merge K=32: ROW_HALF_MIRROR, xor8 = lane^2, xor4 = lane^1, locals
        MIR(0x141, lo4);
        XD(0x4E, lo2);
        XD(0xB1, lo1);
        CE(k0, k2); CE(k1, k3);
        CE(k0, k1); CE(k2, k3);
        // merge K=64: ROW_MIRROR, xor16 = lane^4 (swizzle), xor8, xor4, locals
        MIR(0x140, lo8);
        XS4(lo4);
        XD(0x4E, lo2);
        XD(0xB1, lo1);
        CE(k0, k2); CE(k1, k3);
        CE(k0, k1); CE(k2, k3);

        // ---- gather z in ascending-sorted order via LDS ----
        const float zs0 = zbase[63 - (int)(k0 & 63u)];
        const float zs1 = zbase[63 - (int)(k1 & 63u)];
        const float zs2 = zbase[63 - (int)(k2 & 63u)];
        const float zs3 = zbase[63 - (int)(k3 & 63u)];

        // ---- inclusive prefix scan of per-lane sums within 16-lane row, pure DPP ----
        const float Qs = (zs0 + zs1) + (zs2 + zs3);
        float P = Qs;
        P = dpp_addf<0x111>(P);   // row_shr:1
        P = dpp_addf<0x112>(P);   // row_shr:2
        P = dpp_addf<0x114>(P);   // row_shr:4
        P = dpp_addf<0x118>(P);   // row_shr:8
        const float S0 = (P - Qs) + zs0;    // inclusive prefix at sorted pos 4q..4q+3
        const float S1 = S0 + zs1;
        const float S2 = S1 + zs2;
        const float S3 = S2 + zs3;
        // product of 4 prefix sums <= ~1e18: safely in fp32 range; one log per 4 elems
        acc += __logf((S0 * S1) * (S2 * S3));

        mc = mn_; vc = vn_; tc = tn_;
    }
    #undef CE
    #undef MIR
    #undef XD
    #undef XS4

    // ---- wave + block reduction, per-block partial ----
    #pragma unroll
    for (int off = 32; off > 0; off >>= 1)
        acc += __shfl_xor(acc, off, 64);

    __shared__ float sacc[TPB / 64];
    if (lane == 0) sacc[wIB] = acc;
    __syncthreads();
    if (threadIdx.x == 0) {
        float b = 0.0f;
        #pragma unroll
        for (int i = 0; i < TPB / 64; ++i) b += sacc[i];
        partial[blockIdx.x] = b;
    }
}

__global__ __launch_bounds__(TPB) void mledis_final_reduce(
    const float* __restrict__ partial, float* __restrict__ out)
{
    float s = 0.0f;
    for (int i = threadIdx.x; i < BLOCKS; i += TPB) s += partial[i];
    #pragma unroll
    for (int off = 32; off > 0; off >>= 1) s += __shfl_xor(s, off, 64);

    __shared__ float sacc[TPB / 64];
    const int lane = threadIdx.x & 63;
    const int w = threadIdx.x >> 6;
    if (lane == 0) sacc[w] = s;
    __syncthreads();
    if (threadIdx.x == 0) {
        float tot = 0.0f;
        #pragma unroll
        for (int i = 0; i < TPB / 64; ++i) tot += sacc[i];
        out[0] = tot * (1.0f / (float)N_TOTAL);   // mean over SEG then / b == / N
    }
}

extern "C" void kernel_launch(void* const* d_in, const int* in_sizes, int n_in,
                              void* d_out, int out_size, void* d_ws, size_t ws_size,
                              hipStream_t stream) {
    const float4* mean4 = (const float4*)d_in[0];
    const float4* var4  = (const float4*)d_in[1];
    const int4*   tgt4  = (const int4*)d_in[2];
    // d_in[3] is scope (==64), baked in as SEG

    float* partial = (float*)d_ws;   // BLOCKS floats = 8 KB
    float* out = (float*)d_out;

    mledis_seg4<<<BLOCKS, TPB, 0, stream>>>(mean4, var4, tgt4, partial);
    mledis_final_reduce<<<1, TPB, 0, stream>>>(partial, out);
}

// Round 2
// 119.441 us; speedup vs baseline: 1.0278x; 1.0043x over previous
//
#include <hip/hip_runtime.h>

// Problem constants (fixed by reference setup_inputs)
#define N_TOTAL 8388608
#define SEG 64
#define NSEG (N_TOTAL / SEG)            // 131072 segments
#define TPB 256
#define BLOCKS 2048                     // 8 blocks/CU = 32 waves/CU: ONE resident generation
#define WAVES (BLOCKS * TPB / 64)       // 8192 waves
#define SPW 4                           // segments per wave-iteration (4 x 16-lane groups)
#define ITERS (NSEG / (WAVES * SPW))    // 4 iterations per wave (exact)

// DPP ctrl encodings (gfx9/CDNA):
//   quad_perm [1,0,3,2] = 0xB1 (lane^1), [2,3,0,1] = 0x4E (lane^2),
//   [3,2,1,0] = 0x1B (mirror-in-quad), ROW_MIRROR = 0x140,
//   ROW_HALF_MIRROR = 0x141, row_shr:N = 0x110|N
template <int CTRL>
__device__ __forceinline__ unsigned dppmov(unsigned v) {
    return (unsigned)__builtin_amdgcn_update_dpp(0, (int)v, CTRL, 0xf, 0xf, true);
}
template <int CTRL>
__device__ __forceinline__ float dpp_addf(float x) {
    int mv = __builtin_amdgcn_update_dpp(0, __float_as_int(x), CTRL, 0xf, 0xf, true);
    return x + __int_as_float(mv);
}
__device__ __forceinline__ unsigned umn(unsigned a, unsigned b) { return a < b ? a : b; }
__device__ __forceinline__ unsigned umx(unsigned a, unsigned b) { return a > b ? a : b; }

// One wave processes FOUR 64-element segments per iteration:
//   16-lane group g = lane>>4 owns one segment; lane q = lane&15 holds
//   elements e = 4q..4q+3 (registers k0..k3).
// ASCENDING mirror-form bitonic sort of keys (t<<6)|(63-e) == exact reverse
// of the reference's stable descending argsort(-t) (keys distinct, so the
// cross-lane select uses take = (o<k) XOR hi: v_cmp + s_xor_b64(SGPR role
// mask, free) + v_cndmask = 3 VALU/reg instead of min+max+cndmask).
// Prefetch reloads the SAME mc/vc/tc registers right after they are consumed
// (before the sort), keeping the live set under the 64-VGPR / 8-wave cap.
__global__ __launch_bounds__(TPB, 8) void mledis_seg4(
    const float4* __restrict__ mean4,
    const float4* __restrict__ var4,
    const int4*   __restrict__ tgt4,
    float* __restrict__ partial)
{
    const int lane = threadIdx.x & 63;
    const int q    = lane & 15;          // lane within 16-lane segment group
    const int wIB  = threadIdx.x >> 6;
    const int waveId = blockIdx.x * (TPB / 64) + wIB;

    __shared__ __align__(16) float zbuf[TPB / 64][64 * SPW];   // 4 KB/block
    float* const zbase = &zbuf[wIB][(lane >> 4) * 64];

    // loop-invariant role predicates (live as SGPR lane-masks)
    const bool hi1 = (q & 1) != 0;
    const bool hi2 = (q & 2) != 0;
    const bool hi4 = (q & 4) != 0;
    const bool hi8 = (q & 8) != 0;

    float4 mc = mean4[waveId * 64 + lane];
    float4 vc = var4 [waveId * 64 + lane];
    int4   tc = tgt4 [waveId * 64 + lane];

    float acc = 0.0f;

    // ascending in-register compare-exchange (compile-time roles)
    #define CE(a, b) { const unsigned _mn = umn(a, b); const unsigned _mx = umx(a, b); \
                       a = _mn; b = _mx; }
    // divergent-role select: keep min on lo lanes, max on hi lanes.
    // keys are distinct => (o<k) XOR hi is exact.
    #define SEL(k, o, HI) { k = (((o) < (k)) != (HI)) ? (o) : (k); }
    // mirror merge stage: partner lane via DPP ctrl, partner holds reg 3-r
    #define MIR(CTRL, HI) { \
        const unsigned o0 = dppmov<CTRL>(k3); \
        const unsigned o1 = dppmov<CTRL>(k2); \
        const unsigned o2 = dppmov<CTRL>(k1); \
        const unsigned o3 = dppmov<CTRL>(k0); \
        SEL(k0, o0, HI) SEL(k1, o1, HI) SEL(k2, o2, HI) SEL(k3, o3, HI) \
    }
    // xor cleanup stage via DPP (same reg index from partner lane)
    #define XD(CTRL, HI) { \
        const unsigned o0 = dppmov<CTRL>(k0); \
        const unsigned o1 = dppmov<CTRL>(k1); \
        const unsigned o2 = dppmov<CTRL>(k2); \
        const unsigned o3 = dppmov<CTRL>(k3); \
        SEL(k0, o0, HI) SEL(k1, o1, HI) SEL(k2, o2, HI) SEL(k3, o3, HI) \
    }
    // xor cleanup stage lane^4 via ds_swizzle (BitMode: (4<<10)|0x1F)
    #define XS4(HI) { \
        const unsigned o0 = (unsigned)__builtin_amdgcn_ds_swizzle((int)k0, 0x101F); \
        const unsigned o1 = (unsigned)__builtin_amdgcn_ds_swizzle((int)k1, 0x101F); \
        const unsigned o2 = (unsigned)__builtin_amdgcn_ds_swizzle((int)k2, 0x101F); \
        const unsigned o3 = (unsigned)__builtin_amdgcn_ds_swizzle((int)k3, 0x101F); \
        SEL(k0, o0, HI) SEL(k1, o1, HI) SEL(k2, o2, HI) SEL(k3, o3, HI) \
    }

    #pragma unroll
    for (int it = 0; it < ITERS; ++it) {
        // ---- consume current inputs ----
        // z = exp(m + v/2), stored REVERSED: zbase[63-e] = z_e, so the
        // post-sort gather is zbase[key&63] with no index arithmetic.
        const float z0 = __expf(fmaf(0.5f, vc.x, mc.x));
        const float z1 = __expf(fmaf(0.5f, vc.y, mc.y));
        const float z2 = __expf(fmaf(0.5f, vc.z, mc.z));
        const float z3 = __expf(fmaf(0.5f, vc.w, mc.w));
        *(float4*)(zbase + (60 - 4 * q)) = make_float4(z3, z2, z1, z0);

        // order-invariant part: sum(v/2 - m)
        acc += fmaf(0.5f, (vc.x + vc.y) + (vc.z + vc.w),
                    -((mc.x + mc.y) + (mc.z + mc.w)));

        // distinct keys; ascending sort == reverse of stable descending argsort(-t)
        const unsigned eb = 63u - 4u * (unsigned)q;
        unsigned k0 = (((unsigned)tc.x) << 6) + eb;
        unsigned k1 = (((unsigned)tc.y) << 6) + (eb - 1u);
        unsigned k2 = (((unsigned)tc.z) << 6) + (eb - 2u);
        unsigned k3 = (((unsigned)tc.w) << 6) + (eb - 3u);

        // ---- prefetch next iteration into the SAME registers (current is
        // fully consumed); loads issue here, results needed only after the
        // ~180-instruction sort => latency fully hidden, no extra VGPRs ----
        if (it + 1 < ITERS) {
            const int b = (waveId + (it + 1) * WAVES) * 64 + lane;
            mc = mean4[b]; vc = var4[b]; tc = tgt4[b];
        }

        // ---- all-ascending mirror-form bitonic sort over 64 elements ----
        // merge K=2
        CE(k0, k1); CE(k2, k3);
        // merge K=4: mirror (0<->3, 1<->2) then xor1 — in-register, compile-time
        CE(k0, k3); CE(k1, k2);
        CE(k0, k1); CE(k2, k3);
        // merge K=8: mirror lane^1 (reg-swapped), then local xor2/xor1
        MIR(0xB1, hi1);
        CE(k0, k2); CE(k1, k3);
        CE(k0, k1); CE(k2, k3);
        // merge K=16: mirror-in-quad, xor4 = lane^1, local xor2/xor1
        MIR(0x1B, hi2);
        XD(0xB1, hi1);
        CE(k0, k2); CE(k1, k3);
        CE(k0, k1); CE(k2, k3);
        // merge K=32: ROW_HALF_MIRROR, xor8 = lane^2, xor4 = lane^1, locals
        MIR(0x141, hi4);
        XD(0x4E, hi2);
        XD(0xB1, hi1);
        CE(k0, k2); CE(k1, k3);
        CE(k0, k1); CE(k2, k3);
        // merge K=64: ROW_MIRROR, xor16 = lane^4 (swizzle), xor8, xor4, locals
        MIR(0x140, hi8);
        XS4(hi4);
        XD(0x4E, hi2);
        XD(0xB1, hi1);
        CE(k0, k2); CE(k1, k3);
        CE(k0, k1); CE(k2, k3);

        // ---- gather z in ascending-sorted order (reversed store => direct) ----
        const float zs0 = zbase[(int)(k0 & 63u)];
        const float zs1 = zbase[(int)(k1 & 63u)];
        const float zs2 = zbase[(int)(k2 & 63u)];
        const float zs3 = zbase[(int)(k3 & 63u)];

        // ---- inclusive prefix scan of per-lane sums within 16-lane row, pure DPP ----
        const float Qs = (zs0 + zs1) + (zs2 + zs3);
        float P = Qs;
        P = dpp_addf<0x111>(P);   // row_shr:1
        P = dpp_addf<0x112>(P);   // row_shr:2
        P = dpp_addf<0x114>(P);   // row_shr:4
        P = dpp_addf<0x118>(P);   // row_shr:8
        const float S0 = (P - Qs) + zs0;    // inclusive prefix at sorted pos 4q..4q+3
        const float S1 = S0 + zs1;
        const float S2 = S1 + zs2;
        const float S3 = S2 + zs3;
        // product of 4 prefix sums <= ~1e18: safely in fp32 range; one log per 4 elems
        acc += __logf((S0 * S1) * (S2 * S3));
    }
    #undef CE
    #undef SEL
    #undef MIR
    #undef XD
    #undef XS4

    // ---- wave + block reduction, per-block partial ----
    #pragma unroll
    for (int off = 32; off > 0; off >>= 1)
        acc += __shfl_xor(acc, off, 64);

    __shared__ float sacc[TPB / 64];
    if (lane == 0) sacc[wIB] = acc;
    __syncthreads();
    if (threadIdx.x == 0) {
        float b = 0.0f;
        #pragma unroll
        for (int i = 0; i < TPB / 64; ++i) b += sacc[i];
        partial[blockIdx.x] = b;
    }
}

__global__ __launch_bounds__(TPB) void mledis_final_reduce(
    const float* __restrict__ partial, float* __restrict__ out)
{
    float s = 0.0f;
    for (int i = threadIdx.x; i < BLOCKS; i += TPB) s += partial[i];
    #pragma unroll
    for (int off = 32; off > 0; off >>= 1) s += __shfl_xor(s, off, 64);

    __shared__ float sacc[TPB / 64];
    const int lane = threadIdx.x & 63;
    const int w = threadIdx.x >> 6;
    if (lane == 0) sacc[w] = s;
    __syncthreads();
    if (threadIdx.x == 0) {
        float tot = 0.0f;
        #pragma unroll
        for (int i = 0; i < TPB / 64; ++i) tot += sacc[i];
        out[0] = tot * (1.0f / (float)N_TOTAL);   // mean over SEG then / b == / N
    }
}

extern "C" void kernel_launch(void* const* d_in, const int* in_sizes, int n_in,
                              void* d_out, int out_size, void* d_ws, size_t ws_size,
                              hipStream_t stream) {
    const float4* mean4 = (const float4*)d_in[0];
    const float4* var4  = (const float4*)d_in[1];
    const int4*   tgt4  = (const int4*)d_in[2];
    // d_in[3] is scope (==64), baked in as SEG

    float* partial = (float*)d_ws;   // BLOCKS floats = 8 KB
    float* out = (float*)d_out;

    mledis_seg4<<<BLOCKS, TPB, 0, stream>>>(mean4, var4, tgt4, partial);
    mledis_final_reduce<<<1, TPB, 0, stream>>>(partial, out);
}